// Round 3
// baseline (955.278 us; speedup 1.0000x reference)
//
#include <hip/hip_runtime.h>

using bf16x8 = __attribute__((ext_vector_type(8))) short;
using f32x4  = __attribute__((ext_vector_type(4))) float;

static constexpr int EMB = 512, HEADS = 16, NTOK = 64, BWIN = 2048;
static constexpr int MROWS = BWIN * NTOK;   // 131072
static constexpr int QKVN  = 3 * EMB;       // 1536

__device__ __forceinline__ float bf2f(unsigned int u) {
  union { unsigned int i; float f; } c; c.i = u << 16; return c.f;
}
__device__ __forceinline__ unsigned short f2bf(float x) {
  union { float f; unsigned int i; } c; c.f = x;
  return (unsigned short)((c.i + 0x7fffu + ((c.i >> 16) & 1u)) >> 16);
}
__device__ __forceinline__ void gload_lds16(const void* g, void* l) {
  __builtin_amdgcn_global_load_lds((const __attribute__((address_space(1))) void*)g,
                                   (__attribute__((address_space(3))) void*)l, 16, 0, 0);
}

// ---------------- xcast: x (fp32) -> bf16, one shot ----------------
__global__ __launch_bounds__(256) void xcast(const float* __restrict__ x,
                                             unsigned short* __restrict__ xb) {
  size_t i = ((size_t)blockIdx.x * 256 + threadIdx.x) * 8;   // 32768 blocks cover 2^26 elems
  float4 a = *(const float4*)(x + i);
  float4 b = *(const float4*)(x + i + 4);
  ushort4 lo = make_ushort4(f2bf(a.x), f2bf(a.y), f2bf(a.z), f2bf(a.w));
  ushort4 hi = make_ushort4(f2bf(b.x), f2bf(b.y), f2bf(b.z), f2bf(b.w));
  *(ushort4*)(xb + i) = lo;
  *(ushort4*)(xb + i + 4) = hi;
}

// ---------------- prep: weights -> bf16, build fused qkv bias ----------------
__global__ void prep_weights(const float* __restrict__ qkv_w, const float* __restrict__ proj_w,
                             const float* __restrict__ q_bias, const float* __restrict__ v_bias,
                             unsigned short* __restrict__ wq, unsigned short* __restrict__ wp,
                             float* __restrict__ qkv_bias) {
  int i = blockIdx.x * 256 + threadIdx.x;          // grid covers 786432 = |qkv_w|
  wq[i] = f2bf(qkv_w[i]);
  if (i < EMB * EMB) wp[i] = f2bf(proj_w[i]);
  if (i < EMB) {
    qkv_bias[i]           = q_bias[i];
    qkv_bias[EMB + i]     = 0.f;                   // k bias is zero in reference
    qkv_bias[2 * EMB + i] = v_bias[i];
  }
}

// ---------------- CPB MLP: 225 positions -> (225,16) raw logits ----------------
__global__ __launch_bounds__(64) void cpb_mlp(const float* __restrict__ tbl,
                        const float* __restrict__ w1, const float* __restrict__ b1,
                        const float* __restrict__ w2, float* __restrict__ tab) {
  __shared__ float hid[512];
  const int p = blockIdx.x, t = threadIdx.x;
  const float t0 = tbl[p * 2], t1 = tbl[p * 2 + 1];
  #pragma unroll
  for (int s = 0; s < 8; ++s) {
    int j = t + s * 64;
    hid[j] = fmaxf(0.f, t0 * w1[j * 2] + t1 * w1[j * 2 + 1] + b1[j]);
  }
  __syncthreads();
  const int h = t >> 2, q = t & 3;
  float sum = 0.f;
  for (int j = q * 128; j < q * 128 + 128; ++j) sum += hid[j] * w2[h * 512 + j];
  sum += __shfl_xor(sum, 1);
  sum += __shfl_xor(sum, 2);
  if (q == 0) tab[p * 16 + h] = sum;
}

// ---------------- expand: bias16[h][i][j] = 16*sigmoid(tab[rel_index[i][j]][h]) --------
__global__ void cpb_expand(const float* __restrict__ tab, const int* __restrict__ rel_index,
                           float* __restrict__ bias16) {
  int e = blockIdx.x * 256 + threadIdx.x;   // 65536 total
  int h = e >> 12, ij = e & 4095;
  float x = tab[rel_index[ij] * 16 + h];
  bias16[e] = 16.f / (1.f + __expf(-x));
}

// ---------------- NT GEMM: C(MxN) = A(MxK) * B(NxK)^T + bias ----------------
// 128x128 tile, BK=64, 4 waves each 64x64 out. 2-PHASE double-buffered (T3-lite):
// issue next K-tile's global_load_lds BEFORE current tile's ds_read+MFMA; ONE
// barrier per K-step (its vmcnt(0) drain lands after the compute, not before).
// T2 XOR-swizzled LDS slots with inverse swizzle on the global SOURCE (rule #21).
// T1 XCD-bijective 1D grid, N-fastest per XCD chunk (B panel L2-resident).
template<bool OUT_F32, int NBX, int KT>
__global__ __launch_bounds__(256) void gemm_nt(const unsigned short* __restrict__ Ap,
    const unsigned short* __restrict__ Bp, const float* __restrict__ bias,
    void* __restrict__ Cp, int M, int N) {
  __shared__ unsigned short As[2][128 * 64];
  __shared__ unsigned short Bs[2][128 * 64];
  const int tid = threadIdx.x;
  const int l = tid & 63, w = tid >> 6;
  const int lr = l & 15, lg = l >> 4;
  const int q8 = gridDim.x >> 3;                       // gridDim.x % 8 == 0
  const int wgid = (blockIdx.x & 7) * q8 + (blockIdx.x >> 3);
  const int n0 = (wgid % NBX) * 128, m0 = (wgid / NBX) * 128;
  const int wm = (w >> 1) * 64, wn = (w & 1) * 64;
  const int r8 = l >> 3;
  const int src8 = ((l & 7) ^ r8) * 8;                 // inverse-swizzled source slot
  const unsigned short* Abase = Ap + (size_t)m0 * KT;
  const unsigned short* Bbase = Bp + (size_t)n0 * KT;

  f32x4 acc[4][4];
  #pragma unroll
  for (int i = 0; i < 4; ++i)
    #pragma unroll
    for (int j = 0; j < 4; ++j) acc[i][j] = (f32x4){0.f, 0.f, 0.f, 0.f};

  auto stage = [&](int buf, int k0) {
    #pragma unroll
    for (int it = 0; it < 4; ++it) {
      int c = it * 4 + w;                              // 1KB chunk id (8 rows)
      int row = c * 8 + r8;
      gload_lds16(Abase + (size_t)row * KT + k0 + src8, &As[buf][c * 512]);
      gload_lds16(Bbase + (size_t)row * KT + k0 + src8, &Bs[buf][c * 512]);
    }
  };

  stage(0, 0);
  __syncthreads();                                     // drains vmcnt(0)
  constexpr int NTILES = KT / 64;
  #pragma unroll
  for (int t = 0; t < NTILES; ++t) {
    const int cur = t & 1;
    if (t + 1 < NTILES) stage(cur ^ 1, (t + 1) * 64);  // overlap with compute below
    #pragma unroll
    for (int ks = 0; ks < 2; ++ks) {
      bf16x8 af[4], bfr[4];
      #pragma unroll
      for (int i = 0; i < 4; ++i) {
        int row = wm + i * 16 + lr;
        af[i] = *(const bf16x8*)(&As[cur][row * 64 + (((ks * 4 + lg) ^ (row & 7)) * 8)]);
      }
      #pragma unroll
      for (int j = 0; j < 4; ++j) {
        int row = wn + j * 16 + lr;
        bfr[j] = *(const bf16x8*)(&Bs[cur][row * 64 + (((ks * 4 + lg) ^ (row & 7)) * 8)]);
      }
      #pragma unroll
      for (int i = 0; i < 4; ++i)
        #pragma unroll
        for (int j = 0; j < 4; ++j)
          acc[i][j] = __builtin_amdgcn_mfma_f32_16x16x32_bf16(af[i], bfr[j], acc[i][j], 0, 0, 0);
    }
    __syncthreads();                                   // one barrier per K-step
  }
  #pragma unroll
  for (int i = 0; i < 4; ++i)
    #pragma unroll
    for (int j = 0; j < 4; ++j)
      #pragma unroll
      for (int r = 0; r < 4; ++r) {
        int mm = m0 + wm + i * 16 + lg * 4 + r;
        int nn = n0 + wn + j * 16 + lr;
        float v = acc[i][j][r] + bias[nn];
        if (OUT_F32) ((float*)Cp)[(size_t)mm * N + nn] = v;
        else ((unsigned short*)Cp)[(size_t)mm * N + nn] = f2bf(v);
      }
}

// ---------------- fused window attention: one wave per (window, head) ----------------
// block = 2 waves = heads (2p, 2p+1) of window b  -> both halves of 128B qkv lines used.
__device__ __forceinline__ bf16x8 load_norm_frag(const unsigned short* p, float s) {
  uint4 raw = *(const uint4*)p;
  float f[8];
  f[0] = bf2f(raw.x & 0xffffu); f[1] = bf2f(raw.x >> 16);
  f[2] = bf2f(raw.y & 0xffffu); f[3] = bf2f(raw.y >> 16);
  f[4] = bf2f(raw.z & 0xffffu); f[5] = bf2f(raw.z >> 16);
  f[6] = bf2f(raw.w & 0xffffu); f[7] = bf2f(raw.w >> 16);
  float ss = 0.f;
  #pragma unroll
  for (int j = 0; j < 8; ++j) ss += f[j] * f[j];
  ss += __shfl_xor(ss, 16);                 // reduce over the 4 k-groups (lanes ^16, ^32)
  ss += __shfl_xor(ss, 32);
  float inv = s / fmaxf(sqrtf(ss), 1e-12f);
  bf16x8 v;
  #pragma unroll
  for (int j = 0; j < 8; ++j) v[j] = (short)f2bf(f[j] * inv);
  return v;
}

__global__ __launch_bounds__(128) void attn_win(const unsigned short* __restrict__ qkv,
    const float* __restrict__ bias16, const float* __restrict__ flex,
    unsigned short* __restrict__ aout) {
  __shared__ float sS[2][64 * 65];          // fp32 logits, stride 65 (conflict-free)
  __shared__ unsigned short sP[2][64 * 72]; // bf16 P, stride 72 (2-way = free)
  __shared__ float sRs[2][64];
  const int w = threadIdx.x >> 6, l = threadIdx.x & 63;
  const int lr = l & 15, lg = l >> 4;
  const int b = blockIdx.x >> 3;
  const int h = ((blockIdx.x & 7) << 1) | w;
  const unsigned short* base = qkv + (size_t)b * NTOK * QKVN;
  const float scale = __expf(fminf(flex[h], 4.6051701860f));   // min(flex, ln 100)

  // q (scale folded in) and k fragments, L2-normalized in-register
  bf16x8 aq[4], bk[4];
  #pragma unroll
  for (int i = 0; i < 4; ++i)
    aq[i] = load_norm_frag(base + (size_t)(i * 16 + lr) * QKVN + h * 32 + lg * 8, scale);
  #pragma unroll
  for (int i = 0; i < 4; ++i)
    bk[i] = load_norm_frag(base + (size_t)(i * 16 + lr) * QKVN + EMB + h * 32 + lg * 8, 1.f);

  // S = (scale * qn) @ kn^T
  const f32x4 z = (f32x4){0.f, 0.f, 0.f, 0.f};
  f32x4 sacc[4][4];
  #pragma unroll
  for (int i = 0; i < 4; ++i)
    #pragma unroll
    for (int j = 0; j < 4; ++j)
      sacc[i][j] = __builtin_amdgcn_mfma_f32_16x16x32_bf16(aq[i], bk[j], z, 0, 0, 0);

  // S + bias -> LDS
  float* S = sS[w];
  const float* bh = bias16 + (size_t)h * 4096;
  #pragma unroll
  for (int i = 0; i < 4; ++i)
    #pragma unroll
    for (int j = 0; j < 4; ++j)
      #pragma unroll
      for (int r = 0; r < 4; ++r) {
        int row = i * 16 + lg * 4 + r, col = j * 16 + lr;
        S[row * 65 + col] = sacc[i][j][r] + bh[row * 64 + col];
      }
  __syncthreads();

  // per-lane row softmax (lane l owns row l); P = unnormalized exp (<=1), bf16
  float rowv[64];
  float mx = -1e30f;
  #pragma unroll
  for (int j = 0; j < 64; ++j) { rowv[j] = S[l * 65 + j]; mx = fmaxf(mx, rowv[j]); }
  float sum = 0.f;
  unsigned short* P = sP[w];
  #pragma unroll
  for (int j = 0; j < 64; ++j) {
    float e = __expf(rowv[j] - mx);
    sum += e;
    P[l * 72 + j] = f2bf(e);
  }
  sRs[w][l] = 1.f / sum;
  __syncthreads();

  // stage V^T into (dead) S area: vT[d][tok], stride 72
  unsigned short* vT = (unsigned short*)sS[w];
  {
    const uint4* vp = (const uint4*)(base + (size_t)l * QKVN + 2 * EMB + h * 32);
    uint4 r0 = vp[0], r1 = vp[1], r2 = vp[2], r3 = vp[3];
    unsigned int wd[16] = {r0.x, r0.y, r0.z, r0.w, r1.x, r1.y, r1.z, r1.w,
                           r2.x, r2.y, r2.z, r2.w, r3.x, r3.y, r3.z, r3.w};
    #pragma unroll
    for (int d = 0; d < 32; ++d) {
      unsigned short val = (d & 1) ? (unsigned short)(wd[d >> 1] >> 16)
                                   : (unsigned short)(wd[d >> 1] & 0xffffu);
      vT[d * 72 + l] = val;
    }
  }
  __syncthreads();

  // O = P @ V  (B operand = vT rows, k-contiguous)
  f32x4 oacc[4][2];
  #pragma unroll
  for (int i = 0; i < 4; ++i) { oacc[i][0] = z; oacc[i][1] = z; }
  #pragma unroll
  for (int ks = 0; ks < 2; ++ks) {
    bf16x8 ap[4], bv[2];
    #pragma unroll
    for (int i = 0; i < 4; ++i)
      ap[i] = *(const bf16x8*)(P + (i * 16 + lr) * 72 + ks * 32 + lg * 8);
    #pragma unroll
    for (int jd = 0; jd < 2; ++jd)
      bv[jd] = *(const bf16x8*)(vT + (jd * 16 + lr) * 72 + ks * 32 + lg * 8);
    #pragma unroll
    for (int i = 0; i < 4; ++i)
      #pragma unroll
      for (int jd = 0; jd < 2; ++jd)
        oacc[i][jd] = __builtin_amdgcn_mfma_f32_16x16x32_bf16(ap[i], bv[jd], oacc[i][jd], 0, 0, 0);
  }
  // write attn-out (B,N,H*D) bf16, normalizing by rowsum
  #pragma unroll
  for (int i = 0; i < 4; ++i)
    #pragma unroll
    for (int jd = 0; jd < 2; ++jd)
      #pragma unroll
      for (int r = 0; r < 4; ++r) {
        int tok = i * 16 + lg * 4 + r, d = jd * 16 + lr;
        float val = oacc[i][jd][r] * sRs[w][tok];
        aout[(size_t)(b * NTOK + tok) * EMB + h * 32 + d] = f2bf(val);
      }
}

// ---------------- launch ----------------
extern "C" void kernel_launch(void* const* d_in, const int* in_sizes, int n_in,
                              void* d_out, int out_size, void* d_ws, size_t ws_size,
                              hipStream_t stream) {
  const float* x         = (const float*)d_in[0];
  const float* qkv_w     = (const float*)d_in[1];
  const float* q_bias    = (const float*)d_in[2];
  const float* v_bias    = (const float*)d_in[3];
  const float* flex      = (const float*)d_in[4];
  const float* cpb_w1    = (const float*)d_in[5];
  const float* cpb_b1    = (const float*)d_in[6];
  const float* cpb_w2    = (const float*)d_in[7];
  const float* proj_w    = (const float*)d_in[8];
  const float* proj_b    = (const float*)d_in[9];
  const float* rel_table = (const float*)d_in[10];
  const int*   rel_index = (const int*)d_in[11];

  char* ws = (char*)d_ws;
  unsigned short* qkv_bf = (unsigned short*)(ws + 0);                  // 402,653,184 B
  // xb (bf16 x) and ao_bf ALIAS: xb dies when the QKV GEMM finishes; ao_bf is
  // born at attn_win. Both are 134,217,728 B and fully rewritten every call.
  unsigned short* xb     = (unsigned short*)(ws + 402653184ull);
  unsigned short* ao_bf  = (unsigned short*)(ws + 402653184ull);
  unsigned short* wq_bf  = (unsigned short*)(ws + 536870912ull);       //   1,572,864 B
  unsigned short* wp_bf  = (unsigned short*)(ws + 538443776ull);       //     524,288 B
  float* qkv_bias        = (float*)(ws + 538968064ull);                //       6,144 B
  float* tab             = (float*)(ws + 538974208ull);                //      14,400 B
  float* bias16          = (float*)(ws + 538988608ull);                //     262,144 B

  xcast<<<32768, 256, 0, stream>>>(x, xb);
  prep_weights<<<3072, 256, 0, stream>>>(qkv_w, proj_w, q_bias, v_bias, wq_bf, wp_bf, qkv_bias);
  cpb_mlp<<<225, 64, 0, stream>>>(rel_table, cpb_w1, cpb_b1, cpb_w2, tab);
  cpb_expand<<<256, 256, 0, stream>>>(tab, rel_index, bias16);
  gemm_nt<false, 12, EMB><<<12288, 256, 0, stream>>>(
      xb, wq_bf, qkv_bias, (void*)qkv_bf, MROWS, QKVN);
  attn_win<<<BWIN * 8, 128, 0, stream>>>(qkv_bf, bias16, flex, ao_bf);
  gemm_nt<true, 4, EMB><<<4096, 256, 0, stream>>>(
      ao_bf, wp_bf, proj_b, d_out, MROWS, EMB);
}

// Round 4
// 680.038 us; speedup vs baseline: 1.4047x; 1.4047x over previous
//
#include <hip/hip_runtime.h>

using bf16x8 = __attribute__((ext_vector_type(8))) short;
using f32x4  = __attribute__((ext_vector_type(4))) float;

static constexpr int EMB = 512, HEADS = 16, NTOK = 64, BWIN = 2048;
static constexpr int MROWS = BWIN * NTOK;   // 131072
static constexpr int QKVN  = 3 * EMB;       // 1536

__device__ __forceinline__ float bf2f(unsigned int u) {
  union { unsigned int i; float f; } c; c.i = u << 16; return c.f;
}
__device__ __forceinline__ unsigned short f2bf(float x) {
  union { float f; unsigned int i; } c; c.f = x;
  return (unsigned short)((c.i + 0x7fffu + ((c.i >> 16) & 1u)) >> 16);
}
__device__ __forceinline__ void gload_lds16(const void* g, void* l) {
  __builtin_amdgcn_global_load_lds((const __attribute__((address_space(1))) void*)g,
                                   (__attribute__((address_space(3))) void*)l, 16, 0, 0);
}

#define BARRIER() __builtin_amdgcn_s_barrier()
#define LGKM0()  do { asm volatile("s_waitcnt lgkmcnt(0)" ::: "memory"); \
                      __builtin_amdgcn_sched_barrier(0); } while (0)
#define VMCNT2() do { asm volatile("s_waitcnt vmcnt(2)" ::: "memory"); \
                      __builtin_amdgcn_sched_barrier(0); } while (0)

// ---------------- xcast: x (fp32) -> bf16, one shot ----------------
__global__ __launch_bounds__(256) void xcast(const float* __restrict__ x,
                                             unsigned short* __restrict__ xb) {
  size_t i = ((size_t)blockIdx.x * 256 + threadIdx.x) * 8;   // 32768 blocks cover 2^26 elems
  float4 a = *(const float4*)(x + i);
  float4 b = *(const float4*)(x + i + 4);
  ushort4 lo = make_ushort4(f2bf(a.x), f2bf(a.y), f2bf(a.z), f2bf(a.w));
  ushort4 hi = make_ushort4(f2bf(b.x), f2bf(b.y), f2bf(b.z), f2bf(b.w));
  *(ushort4*)(xb + i) = lo;
  *(ushort4*)(xb + i + 4) = hi;
}

// ---------------- prep: weights -> bf16, build fused qkv bias ----------------
__global__ void prep_weights(const float* __restrict__ qkv_w, const float* __restrict__ proj_w,
                             const float* __restrict__ q_bias, const float* __restrict__ v_bias,
                             unsigned short* __restrict__ wq, unsigned short* __restrict__ wp,
                             float* __restrict__ qkv_bias) {
  int i = blockIdx.x * 256 + threadIdx.x;          // grid covers 786432 = |qkv_w|
  wq[i] = f2bf(qkv_w[i]);
  if (i < EMB * EMB) wp[i] = f2bf(proj_w[i]);
  if (i < EMB) {
    qkv_bias[i]           = q_bias[i];
    qkv_bias[EMB + i]     = 0.f;                   // k bias is zero in reference
    qkv_bias[2 * EMB + i] = v_bias[i];
  }
}

// ---------------- CPB MLP: 225 positions -> (225,16) raw logits ----------------
__global__ __launch_bounds__(64) void cpb_mlp(const float* __restrict__ tbl,
                        const float* __restrict__ w1, const float* __restrict__ b1,
                        const float* __restrict__ w2, float* __restrict__ tab) {
  __shared__ float hid[512];
  const int p = blockIdx.x, t = threadIdx.x;
  const float t0 = tbl[p * 2], t1 = tbl[p * 2 + 1];
  #pragma unroll
  for (int s = 0; s < 8; ++s) {
    int j = t + s * 64;
    hid[j] = fmaxf(0.f, t0 * w1[j * 2] + t1 * w1[j * 2 + 1] + b1[j]);
  }
  __syncthreads();
  const int h = t >> 2, q = t & 3;
  float sum = 0.f;
  for (int j = q * 128; j < q * 128 + 128; ++j) sum += hid[j] * w2[h * 512 + j];
  sum += __shfl_xor(sum, 1);
  sum += __shfl_xor(sum, 2);
  if (q == 0) tab[p * 16 + h] = sum;
}

// ---------------- expand: bias16[h][i][j] = 16*sigmoid(tab[rel_index[i][j]][h]) --------
__global__ void cpb_expand(const float* __restrict__ tab, const int* __restrict__ rel_index,
                           float* __restrict__ bias16) {
  int e = blockIdx.x * 256 + threadIdx.x;   // 65536 total
  int h = e >> 12, ij = e & 4095;
  float x = tab[rel_index[ij] * 16 + h];
  bias16[e] = 16.f / (1.f + __expf(-x));
}

// ---------------- 256x256 8-phase NT GEMM (m201-template port) ----------------
// C(MxN) = A(MxK) * B(NxK)^T + bias. BK=64, 8 waves (2Mx4N), per-wave C 128x64.
// LDS 128KB: As[2][256][64] + Bs[2][256][64], 16B-slot XOR swizzle slot^(row&7),
// inverse swizzle on gload_lds SOURCE (rule #21). 8 phases / 2 K-tiles per iter:
//   ph1-4 compute dbuf0 (quadrants (0,0),(0,2),(4,2),(4,0)); ph5-8 dbuf1.
//   Staging stagger: ph8,1,2,3 -> dbuf1's next K-tile; ph4-7 -> dbuf0's next.
//   Counted vmcnt(2) gates at ph4/ph8 ONLY (T4); raw s_barrier (no vmcnt drain);
//   setprio(1) around each 16-MFMA cluster (T5). Tail: staged kt clamped (dead
//   garbage into a consumed buffer, never read).
template<bool OUT_F32, int NBX, int KT>
__global__ __launch_bounds__(512, 2) void gemm256(const unsigned short* __restrict__ Ap,
    const unsigned short* __restrict__ Bp, const float* __restrict__ bias,
    void* __restrict__ Cp, int M, int N) {
  __shared__ unsigned short As[2][256 * 64];
  __shared__ unsigned short Bs[2][256 * 64];
  constexpr int NT = KT / 64;          // K-tiles (8 for K=512)
  constexpr int NITER = NT / 2;
  const int t = threadIdx.x;
  const int l = t & 63, w = t >> 6;
  const int lr = l & 15, lg = l >> 4;
  const int q8 = gridDim.x >> 3;                       // gridDim.x % 8 == 0
  const int wgid = (blockIdx.x & 7) * q8 + (blockIdx.x >> 3);
  const int n0 = (wgid % NBX) * 256, m0 = (wgid / NBX) * 256;
  const int wm = (w >> 2) * 128, wn = (w & 3) * 64;    // wave's C offset in tile
  const int ha128 = (w >> 2) * 128;                    // wave's A half base row
  // staging pattern: thread t covers rows srow, srow+64 of a 128-row half, slot t&7
  const int srow = t >> 3;
  const int scol = ((t & 7) ^ (srow & 7)) << 3;        // inverse-swizzled src col (elems)
  const unsigned short* Abase = Ap + (size_t)m0 * KT;
  const unsigned short* Bbase = Bp + (size_t)n0 * KT;

  f32x4 acc[8][4];
  #pragma unroll
  for (int i = 0; i < 8; ++i)
    #pragma unroll
    for (int j = 0; j < 4; ++j) acc[i][j] = (f32x4){0.f, 0.f, 0.f, 0.f};
  bf16x8 afr[4][2], bfr[4][2];

  auto stage_half = [&](int d, int kt, int half, bool isA) {
    const unsigned short* g = (isA ? Abase : Bbase)
        + (size_t)(half * 128 + srow) * KT + kt * 64 + scol;
    unsigned short* lds = (isA ? &As[d][0] : &Bs[d][0]) + half * 8192 + (t >> 6) * 512;
    gload_lds16(g, lds);                               // rows srow (w*8..w*8+7)
    gload_lds16(g + (size_t)64 * KT, lds + 4096);      // rows srow+64
  };
  auto ldA4 = [&](int d, int mb) {                     // afr <- A frags mb..mb+3, ks 0..1
    #pragma unroll
    for (int m = 0; m < 4; ++m) {
      int row = ha128 + (mb + m) * 16 + lr;
      #pragma unroll
      for (int ks = 0; ks < 2; ++ks)
        afr[m][ks] = *(const bf16x8*)(&As[d][row * 64 + ((((ks << 2) + lg) ^ (lr & 7)) << 3)]);
    }
  };
  auto ldB2 = [&](int d, int nb) {                     // bfr[nb..nb+1] <- B frags
    #pragma unroll
    for (int n = 0; n < 2; ++n) {
      int row = wn + (nb + n) * 16 + lr;
      #pragma unroll
      for (int ks = 0; ks < 2; ++ks)
        bfr[nb + n][ks] = *(const bf16x8*)(&Bs[d][row * 64 + ((((ks << 2) + lg) ^ (lr & 7)) << 3)]);
    }
  };
  auto mfmaQ = [&](int mb, int nb) {                   // 16 MFMA: one C quadrant, K=64
    __builtin_amdgcn_s_setprio(1);
    #pragma unroll
    for (int ks = 0; ks < 2; ++ks)
      #pragma unroll
      for (int m = 0; m < 4; ++m)
        #pragma unroll
        for (int n = 0; n < 2; ++n)
          acc[mb + m][nb + n] = __builtin_amdgcn_mfma_f32_16x16x32_bf16(
              afr[m][ks], bfr[nb + n][ks], acc[mb + m][nb + n], 0, 0, 0);
    __builtin_amdgcn_s_setprio(0);
  };

  // ---- prologue: T0 fully into d0, T1-Ah0 into d1 (mimics ph8 slot) ----
  stage_half(0, 0, 0, true);  stage_half(0, 0, 1, true);
  stage_half(0, 0, 0, false); stage_half(0, 0, 1, false);
  stage_half(1, (NT > 1 ? 1 : 0), 0, true);
  VMCNT2();                                            // T0's 8 loads landed
  BARRIER();

  for (int i = 0; i < NITER; ++i) {
    const int kt1 = 2 * i + 1;                         // always < NT
    const int kt2 = (2 * i + 2 < NT) ? 2 * i + 2 : NT - 1;   // clamped (tail garbage)
    const int kt3 = (2 * i + 3 < NT) ? 2 * i + 3 : NT - 1;
    // PH1: ds A(d0,mf0-3)+B(d0,nf0-1); stage d1<-T(kt1)-Ah1
    ldA4(0, 0); ldB2(0, 0);
    stage_half(1, kt1, 1, true);
    BARRIER(); LGKM0(); mfmaQ(0, 0); BARRIER();
    // PH2: ds B(d0,nf2-3); stage d1<-T(kt1)-Bh0
    ldB2(0, 2);
    stage_half(1, kt1, 0, false);
    BARRIER(); LGKM0(); mfmaQ(0, 2); BARRIER();
    // PH3: ds A(d0,mf4-7); stage d1<-T(kt1)-Bh1   (d0 fully consumed after this)
    ldA4(0, 4);
    stage_half(1, kt1, 1, false);
    BARRIER(); LGKM0(); mfmaQ(4, 2); BARRIER();
    // PH4: stage d0<-T(kt2)-Ah0; GATE vmcnt(2): T(kt1) all landed for ph5-8
    stage_half(0, kt2, 0, true);
    VMCNT2(); BARRIER(); mfmaQ(4, 0); BARRIER();
    // PH5: ds A(d1,mf0-3)+B(d1,nf0-1); stage d0<-T(kt2)-Ah1
    ldA4(1, 0); ldB2(1, 0);
    stage_half(0, kt2, 1, true);
    BARRIER(); LGKM0(); mfmaQ(0, 0); BARRIER();
    // PH6: ds B(d1,nf2-3); stage d0<-T(kt2)-Bh0
    ldB2(1, 2);
    stage_half(0, kt2, 0, false);
    BARRIER(); LGKM0(); mfmaQ(0, 2); BARRIER();
    // PH7: ds A(d1,mf4-7); stage d0<-T(kt2)-Bh1   (d1 fully consumed after this)
    ldA4(1, 4);
    stage_half(0, kt2, 1, false);
    BARRIER(); LGKM0(); mfmaQ(4, 2); BARRIER();
    // PH8: stage d1<-T(kt3)-Ah0; GATE vmcnt(2): T(kt2) all landed for next iter
    stage_half(1, kt3, 0, true);
    VMCNT2(); BARRIER(); mfmaQ(4, 0); BARRIER();
  }

  // ---- epilogue: C = acc + bias ----
  #pragma unroll
  for (int mf = 0; mf < 8; ++mf)
    #pragma unroll
    for (int nf = 0; nf < 4; ++nf)
      #pragma unroll
      for (int r = 0; r < 4; ++r) {
        int mm = m0 + wm + mf * 16 + lg * 4 + r;
        int nn = n0 + wn + nf * 16 + lr;
        float v = acc[mf][nf][r] + bias[nn];
        if (OUT_F32) ((float*)Cp)[(size_t)mm * N + nn] = v;
        else ((unsigned short*)Cp)[(size_t)mm * N + nn] = f2bf(v);
      }
}

// ---------------- fused window attention: one wave per (window, head) ----------------
// block = 2 waves = heads (2p, 2p+1) of window b  -> both halves of 128B qkv lines used.
__device__ __forceinline__ bf16x8 load_norm_frag(const unsigned short* p, float s) {
  uint4 raw = *(const uint4*)p;
  float f[8];
  f[0] = bf2f(raw.x & 0xffffu); f[1] = bf2f(raw.x >> 16);
  f[2] = bf2f(raw.y & 0xffffu); f[3] = bf2f(raw.y >> 16);
  f[4] = bf2f(raw.z & 0xffffu); f[5] = bf2f(raw.z >> 16);
  f[6] = bf2f(raw.w & 0xffffu); f[7] = bf2f(raw.w >> 16);
  float ss = 0.f;
  #pragma unroll
  for (int j = 0; j < 8; ++j) ss += f[j] * f[j];
  ss += __shfl_xor(ss, 16);                 // reduce over the 4 k-groups (lanes ^16, ^32)
  ss += __shfl_xor(ss, 32);
  float inv = s / fmaxf(sqrtf(ss), 1e-12f);
  bf16x8 v;
  #pragma unroll
  for (int j = 0; j < 8; ++j) v[j] = (short)f2bf(f[j] * inv);
  return v;
}

__global__ __launch_bounds__(128) void attn_win(const unsigned short* __restrict__ qkv,
    const float* __restrict__ bias16, const float* __restrict__ flex,
    unsigned short* __restrict__ aout) {
  __shared__ float sS[2][64 * 65];          // fp32 logits, stride 65 (conflict-free)
  __shared__ unsigned short sP[2][64 * 72]; // bf16 P, stride 72 (2-way = free)
  __shared__ float sRs[2][64];
  const int w = threadIdx.x >> 6, l = threadIdx.x & 63;
  const int lr = l & 15, lg = l >> 4;
  const int b = blockIdx.x >> 3;
  const int h = ((blockIdx.x & 7) << 1) | w;
  const unsigned short* base = qkv + (size_t)b * NTOK * QKVN;
  const float scale = __expf(fminf(flex[h], 4.6051701860f));   // min(flex, ln 100)

  // q (scale folded in) and k fragments, L2-normalized in-register
  bf16x8 aq[4], bk[4];
  #pragma unroll
  for (int i = 0; i < 4; ++i)
    aq[i] = load_norm_frag(base + (size_t)(i * 16 + lr) * QKVN + h * 32 + lg * 8, scale);
  #pragma unroll
  for (int i = 0; i < 4; ++i)
    bk[i] = load_norm_frag(base + (size_t)(i * 16 + lr) * QKVN + EMB + h * 32 + lg * 8, 1.f);

  // S = (scale * qn) @ kn^T
  const f32x4 z = (f32x4){0.f, 0.f, 0.f, 0.f};
  f32x4 sacc[4][4];
  #pragma unroll
  for (int i = 0; i < 4; ++i)
    #pragma unroll
    for (int j = 0; j < 4; ++j)
      sacc[i][j] = __builtin_amdgcn_mfma_f32_16x16x32_bf16(aq[i], bk[j], z, 0, 0, 0);

  // S + bias -> LDS
  float* S = sS[w];
  const float* bh = bias16 + (size_t)h * 4096;
  #pragma unroll
  for (int i = 0; i < 4; ++i)
    #pragma unroll
    for (int j = 0; j < 4; ++j)
      #pragma unroll
      for (int r = 0; r < 4; ++r) {
        int row = i * 16 + lg * 4 + r, col = j * 16 + lr;
        S[row * 65 + col] = sacc[i][j][r] + bh[row * 64 + col];
      }
  __syncthreads();

  // per-lane row softmax (lane l owns row l); P = unnormalized exp (<=1), bf16
  float rowv[64];
  float mx = -1e30f;
  #pragma unroll
  for (int j = 0; j < 64; ++j) { rowv[j] = S[l * 65 + j]; mx = fmaxf(mx, rowv[j]); }
  float sum = 0.f;
  unsigned short* P = sP[w];
  #pragma unroll
  for (int j = 0; j < 64; ++j) {
    float e = __expf(rowv[j] - mx);
    sum += e;
    P[l * 72 + j] = f2bf(e);
  }
  sRs[w][l] = 1.f / sum;
  __syncthreads();

  // stage V^T into (dead) S area: vT[d][tok], stride 72
  unsigned short* vT = (unsigned short*)sS[w];
  {
    const uint4* vp = (const uint4*)(base + (size_t)l * QKVN + 2 * EMB + h * 32);
    uint4 r0 = vp[0], r1 = vp[1], r2 = vp[2], r3 = vp[3];
    unsigned int wd[16] = {r0.x, r0.y, r0.z, r0.w, r1.x, r1.y, r1.z, r1.w,
                           r2.x, r2.y, r2.z, r2.w, r3.x, r3.y, r3.z, r3.w};
    #pragma unroll
    for (int d = 0; d < 32; ++d) {
      unsigned short val = (d & 1) ? (unsigned short)(wd[d >> 1] >> 16)
                                   : (unsigned short)(wd[d >> 1] & 0xffffu);
      vT[d * 72 + l] = val;
    }
  }
  __syncthreads();

  // O = P @ V  (B operand = vT rows, k-contiguous)
  f32x4 oacc[4][2];
  #pragma unroll
  for (int i = 0; i < 4; ++i) { oacc[i][0] = z; oacc[i][1] = z; }
  #pragma unroll
  for (int ks = 0; ks < 2; ++ks) {
    bf16x8 ap[4], bv[2];
    #pragma unroll
    for (int i = 0; i < 4; ++i)
      ap[i] = *(const bf16x8*)(P + (i * 16 + lr) * 72 + ks * 32 + lg * 8);
    #pragma unroll
    for (int jd = 0; jd < 2; ++jd)
      bv[jd] = *(const bf16x8*)(vT + (jd * 16 + lr) * 72 + ks * 32 + lg * 8);
    #pragma unroll
    for (int i = 0; i < 4; ++i)
      #pragma unroll
      for (int jd = 0; jd < 2; ++jd)
        oacc[i][jd] = __builtin_amdgcn_mfma_f32_16x16x32_bf16(ap[i], bv[jd], oacc[i][jd], 0, 0, 0);
  }
  // write attn-out (B,N,H*D) bf16, normalizing by rowsum
  #pragma unroll
  for (int i = 0; i < 4; ++i)
    #pragma unroll
    for (int jd = 0; jd < 2; ++jd)
      #pragma unroll
      for (int r = 0; r < 4; ++r) {
        int tok = i * 16 + lg * 4 + r, d = jd * 16 + lr;
        float val = oacc[i][jd][r] * sRs[w][tok];
        aout[(size_t)(b * NTOK + tok) * EMB + h * 32 + d] = f2bf(val);
      }
}

// ---------------- launch ----------------
extern "C" void kernel_launch(void* const* d_in, const int* in_sizes, int n_in,
                              void* d_out, int out_size, void* d_ws, size_t ws_size,
                              hipStream_t stream) {
  const float* x         = (const float*)d_in[0];
  const float* qkv_w     = (const float*)d_in[1];
  const float* q_bias    = (const float*)d_in[2];
  const float* v_bias    = (const float*)d_in[3];
  const float* flex      = (const float*)d_in[4];
  const float* cpb_w1    = (const float*)d_in[5];
  const float* cpb_b1    = (const float*)d_in[6];
  const float* cpb_w2    = (const float*)d_in[7];
  const float* proj_w    = (const float*)d_in[8];
  const float* proj_b    = (const float*)d_in[9];
  const float* rel_table = (const float*)d_in[10];
  const int*   rel_index = (const int*)d_in[11];

  char* ws = (char*)d_ws;
  unsigned short* qkv_bf = (unsigned short*)(ws + 0);                  // 402,653,184 B
  // xb (bf16 x) and ao_bf ALIAS: xb dies when the QKV GEMM finishes; ao_bf is
  // born at attn_win. Both are 134,217,728 B and fully rewritten every call.
  unsigned short* xb     = (unsigned short*)(ws + 402653184ull);
  unsigned short* ao_bf  = (unsigned short*)(ws + 402653184ull);
  unsigned short* wq_bf  = (unsigned short*)(ws + 536870912ull);       //   1,572,864 B
  unsigned short* wp_bf  = (unsigned short*)(ws + 538443776ull);       //     524,288 B
  float* qkv_bias        = (float*)(ws + 538968064ull);                //       6,144 B
  float* tab             = (float*)(ws + 538974208ull);                //      14,400 B
  float* bias16          = (float*)(ws + 538988608ull);                //     262,144 B

  xcast<<<32768, 256, 0, stream>>>(x, xb);
  prep_weights<<<3072, 256, 0, stream>>>(qkv_w, proj_w, q_bias, v_bias, wq_bf, wp_bf, qkv_bias);
  cpb_mlp<<<225, 64, 0, stream>>>(rel_table, cpb_w1, cpb_b1, cpb_w2, tab);
  cpb_expand<<<256, 256, 0, stream>>>(tab, rel_index, bias16);
  // QKV: M=131072, N=1536 -> grid 512*6 = 3072 (divisible by 8)
  gemm256<false, 6, EMB><<<3072, 512, 0, stream>>>(
      xb, wq_bf, qkv_bias, (void*)qkv_bf, MROWS, QKVN);
  attn_win<<<BWIN * 8, 128, 0, stream>>>(qkv_bf, bias16, flex, ao_bf);
  // proj: M=131072, N=512 -> grid 512*2 = 1024 (divisible by 8)
  gemm256<true, 2, EMB><<<1024, 512, 0, stream>>>(
      ao_bf, wp_bf, proj_b, d_out, MROWS, EMB);
}

// Round 5
// 644.709 us; speedup vs baseline: 1.4817x; 1.0548x over previous
//
#include <hip/hip_runtime.h>

using bf16x8 = __attribute__((ext_vector_type(8))) short;
using f32x4  = __attribute__((ext_vector_type(4))) float;

static constexpr int EMB = 512, HEADS = 16, NTOK = 64, BWIN = 2048;
static constexpr int MROWS = BWIN * NTOK;   // 131072
static constexpr int QKVN  = 3 * EMB;       // 1536

__device__ __forceinline__ float bf2f(unsigned int u) {
  union { unsigned int i; float f; } c; c.i = u << 16; return c.f;
}
__device__ __forceinline__ unsigned short f2bf(float x) {
  union { float f; unsigned int i; } c; c.f = x;
  return (unsigned short)((c.i + 0x7fffu + ((c.i >> 16) & 1u)) >> 16);
}
__device__ __forceinline__ void gload_lds16(const void* g, void* l) {
  __builtin_amdgcn_global_load_lds((const __attribute__((address_space(1))) void*)g,
                                   (__attribute__((address_space(3))) void*)l, 16, 0, 0);
}

#define BARRIER() __builtin_amdgcn_s_barrier()
#define LGKM0()  do { asm volatile("s_waitcnt lgkmcnt(0)" ::: "memory"); \
                      __builtin_amdgcn_sched_barrier(0); } while (0)
#define VMCNT2() do { asm volatile("s_waitcnt vmcnt(2)" ::: "memory"); \
                      __builtin_amdgcn_sched_barrier(0); } while (0)

// ---------------- xcast: x (fp32) -> bf16, one shot ----------------
__global__ __launch_bounds__(256) void xcast(const float* __restrict__ x,
                                             unsigned short* __restrict__ xb) {
  size_t i = ((size_t)blockIdx.x * 256 + threadIdx.x) * 8;   // 32768 blocks cover 2^26 elems
  float4 a = *(const float4*)(x + i);
  float4 b = *(const float4*)(x + i + 4);
  ushort4 lo = make_ushort4(f2bf(a.x), f2bf(a.y), f2bf(a.z), f2bf(a.w));
  ushort4 hi = make_ushort4(f2bf(b.x), f2bf(b.y), f2bf(b.z), f2bf(b.w));
  *(ushort4*)(xb + i) = lo;
  *(ushort4*)(xb + i + 4) = hi;
}

// ---------------- prep: weights -> bf16, build fused qkv bias ----------------
__global__ void prep_weights(const float* __restrict__ qkv_w, const float* __restrict__ proj_w,
                             const float* __restrict__ q_bias, const float* __restrict__ v_bias,
                             unsigned short* __restrict__ wq, unsigned short* __restrict__ wp,
                             float* __restrict__ qkv_bias) {
  int i = blockIdx.x * 256 + threadIdx.x;          // grid covers 786432 = |qkv_w|
  wq[i] = f2bf(qkv_w[i]);
  if (i < EMB * EMB) wp[i] = f2bf(proj_w[i]);
  if (i < EMB) {
    qkv_bias[i]           = q_bias[i];
    qkv_bias[EMB + i]     = 0.f;                   // k bias is zero in reference
    qkv_bias[2 * EMB + i] = v_bias[i];
  }
}

// ---------------- CPB MLP: 225 positions -> (225,16) raw logits ----------------
__global__ __launch_bounds__(64) void cpb_mlp(const float* __restrict__ tbl,
                        const float* __restrict__ w1, const float* __restrict__ b1,
                        const float* __restrict__ w2, float* __restrict__ tab) {
  __shared__ float hid[512];
  const int p = blockIdx.x, t = threadIdx.x;
  const float t0 = tbl[p * 2], t1 = tbl[p * 2 + 1];
  #pragma unroll
  for (int s = 0; s < 8; ++s) {
    int j = t + s * 64;
    hid[j] = fmaxf(0.f, t0 * w1[j * 2] + t1 * w1[j * 2 + 1] + b1[j]);
  }
  __syncthreads();
  const int h = t >> 2, q = t & 3;
  float sum = 0.f;
  for (int j = q * 128; j < q * 128 + 128; ++j) sum += hid[j] * w2[h * 512 + j];
  sum += __shfl_xor(sum, 1);
  sum += __shfl_xor(sum, 2);
  if (q == 0) tab[p * 16 + h] = sum;
}

// ---------------- expand: bias16[h][i][j] = 16*sigmoid(tab[rel_index[i][j]][h]) --------
__global__ void cpb_expand(const float* __restrict__ tab, const int* __restrict__ rel_index,
                           float* __restrict__ bias16) {
  int e = blockIdx.x * 256 + threadIdx.x;   // 65536 total
  int h = e >> 12, ij = e & 4095;
  float x = tab[rel_index[ij] * 16 + h];
  bias16[e] = 16.f / (1.f + __expf(-x));
}

// ---------------- 256x256 8-phase NT GEMM (m201-template port) ----------------
// (unchanged from R4: 728 TF on QKV, MfmaUtil 31%, 0 bank conflicts)
template<bool OUT_F32, int NBX, int KT>
__global__ __launch_bounds__(512, 2) void gemm256(const unsigned short* __restrict__ Ap,
    const unsigned short* __restrict__ Bp, const float* __restrict__ bias,
    void* __restrict__ Cp, int M, int N) {
  __shared__ unsigned short As[2][256 * 64];
  __shared__ unsigned short Bs[2][256 * 64];
  constexpr int NT = KT / 64;          // K-tiles (8 for K=512)
  constexpr int NITER = NT / 2;
  const int t = threadIdx.x;
  const int l = t & 63, w = t >> 6;
  const int lr = l & 15, lg = l >> 4;
  const int q8 = gridDim.x >> 3;                       // gridDim.x % 8 == 0
  const int wgid = (blockIdx.x & 7) * q8 + (blockIdx.x >> 3);
  const int n0 = (wgid % NBX) * 256, m0 = (wgid / NBX) * 256;
  const int wm = (w >> 2) * 128, wn = (w & 3) * 64;    // wave's C offset in tile
  const int ha128 = (w >> 2) * 128;                    // wave's A half base row
  const int srow = t >> 3;
  const int scol = ((t & 7) ^ (srow & 7)) << 3;        // inverse-swizzled src col (elems)
  const unsigned short* Abase = Ap + (size_t)m0 * KT;
  const unsigned short* Bbase = Bp + (size_t)n0 * KT;

  f32x4 acc[8][4];
  #pragma unroll
  for (int i = 0; i < 8; ++i)
    #pragma unroll
    for (int j = 0; j < 4; ++j) acc[i][j] = (f32x4){0.f, 0.f, 0.f, 0.f};
  bf16x8 afr[4][2], bfr[4][2];

  auto stage_half = [&](int d, int kt, int half, bool isA) {
    const unsigned short* g = (isA ? Abase : Bbase)
        + (size_t)(half * 128 + srow) * KT + kt * 64 + scol;
    unsigned short* lds = (isA ? &As[d][0] : &Bs[d][0]) + half * 8192 + (t >> 6) * 512;
    gload_lds16(g, lds);                               // rows srow (w*8..w*8+7)
    gload_lds16(g + (size_t)64 * KT, lds + 4096);      // rows srow+64
  };
  auto ldA4 = [&](int d, int mb) {                     // afr <- A frags mb..mb+3, ks 0..1
    #pragma unroll
    for (int m = 0; m < 4; ++m) {
      int row = ha128 + (mb + m) * 16 + lr;
      #pragma unroll
      for (int ks = 0; ks < 2; ++ks)
        afr[m][ks] = *(const bf16x8*)(&As[d][row * 64 + ((((ks << 2) + lg) ^ (lr & 7)) << 3)]);
    }
  };
  auto ldB2 = [&](int d, int nb) {                     // bfr[nb..nb+1] <- B frags
    #pragma unroll
    for (int n = 0; n < 2; ++n) {
      int row = wn + (nb + n) * 16 + lr;
      #pragma unroll
      for (int ks = 0; ks < 2; ++ks)
        bfr[nb + n][ks] = *(const bf16x8*)(&Bs[d][row * 64 + ((((ks << 2) + lg) ^ (lr & 7)) << 3)]);
    }
  };
  auto mfmaQ = [&](int mb, int nb) {                   // 16 MFMA: one C quadrant, K=64
    __builtin_amdgcn_s_setprio(1);
    #pragma unroll
    for (int ks = 0; ks < 2; ++ks)
      #pragma unroll
      for (int m = 0; m < 4; ++m)
        #pragma unroll
        for (int n = 0; n < 2; ++n)
          acc[mb + m][nb + n] = __builtin_amdgcn_mfma_f32_16x16x32_bf16(
              afr[m][ks], bfr[nb + n][ks], acc[mb + m][nb + n], 0, 0, 0);
    __builtin_amdgcn_s_setprio(0);
  };

  // ---- prologue: T0 fully into d0, T1-Ah0 into d1 (mimics ph8 slot) ----
  stage_half(0, 0, 0, true);  stage_half(0, 0, 1, true);
  stage_half(0, 0, 0, false); stage_half(0, 0, 1, false);
  stage_half(1, (NT > 1 ? 1 : 0), 0, true);
  VMCNT2();                                            // T0's 8 loads landed
  BARRIER();

  for (int i = 0; i < NITER; ++i) {
    const int kt1 = 2 * i + 1;                         // always < NT
    const int kt2 = (2 * i + 2 < NT) ? 2 * i + 2 : NT - 1;   // clamped (tail garbage)
    const int kt3 = (2 * i + 3 < NT) ? 2 * i + 3 : NT - 1;
    // PH1: ds A(d0,mf0-3)+B(d0,nf0-1); stage d1<-T(kt1)-Ah1
    ldA4(0, 0); ldB2(0, 0);
    stage_half(1, kt1, 1, true);
    BARRIER(); LGKM0(); mfmaQ(0, 0); BARRIER();
    // PH2: ds B(d0,nf2-3); stage d1<-T(kt1)-Bh0
    ldB2(0, 2);
    stage_half(1, kt1, 0, false);
    BARRIER(); LGKM0(); mfmaQ(0, 2); BARRIER();
    // PH3: ds A(d0,mf4-7); stage d1<-T(kt1)-Bh1   (d0 fully consumed after this)
    ldA4(0, 4);
    stage_half(1, kt1, 1, false);
    BARRIER(); LGKM0(); mfmaQ(4, 2); BARRIER();
    // PH4: stage d0<-T(kt2)-Ah0; GATE vmcnt(2): T(kt1) all landed for ph5-8
    stage_half(0, kt2, 0, true);
    VMCNT2(); BARRIER(); mfmaQ(4, 0); BARRIER();
    // PH5: ds A(d1,mf0-3)+B(d1,nf0-1); stage d0<-T(kt2)-Ah1
    ldA4(1, 0); ldB2(1, 0);
    stage_half(0, kt2, 1, true);
    BARRIER(); LGKM0(); mfmaQ(0, 0); BARRIER();
    // PH6: ds B(d1,nf2-3); stage d0<-T(kt2)-Bh0
    ldB2(1, 2);
    stage_half(0, kt2, 0, false);
    BARRIER(); LGKM0(); mfmaQ(0, 2); BARRIER();
    // PH7: ds A(d1,mf4-7); stage d0<-T(kt2)-Bh1   (d1 fully consumed after this)
    ldA4(1, 4);
    stage_half(0, kt2, 1, false);
    BARRIER(); LGKM0(); mfmaQ(4, 2); BARRIER();
    // PH8: stage d1<-T(kt3)-Ah0; GATE vmcnt(2): T(kt2) all landed for next iter
    stage_half(1, kt3, 0, true);
    VMCNT2(); BARRIER(); mfmaQ(4, 0); BARRIER();
  }

  // ---- epilogue: C = acc + bias ----
  #pragma unroll
  for (int mf = 0; mf < 8; ++mf)
    #pragma unroll
    for (int nf = 0; nf < 4; ++nf)
      #pragma unroll
      for (int r = 0; r < 4; ++r) {
        int mm = m0 + wm + mf * 16 + lg * 4 + r;
        int nn = n0 + wn + nf * 16 + lr;
        float v = acc[mf][nf][r] + bias[nn];
        if (OUT_F32) ((float*)Cp)[(size_t)mm * N + nn] = v;
        else ((unsigned short*)Cp)[(size_t)mm * N + nn] = f2bf(v);
      }
}

// ---------------- fused window attention: ONE WAVE per (window, head) ----------------
// Wave-private LDS, ZERO barriers (same-wave LDS ops are program-ordered; compiler
// fences via asm memory clobber where regions alias). 16.6KB/block -> ~9 blocks/CU.
// XCD swizzle: all 16 heads of a window land on one XCD (qkv panel L2-resident).
// V preloaded to regs before QK^T (T14). P packed b128 writes, stride 72 ushort
// (36 words = 4 mod 32 -> natural bank spread). rowsum broadcast via __shfl.
__device__ __forceinline__ bf16x8 load_norm_frag(const unsigned short* p, float s) {
  uint4 raw = *(const uint4*)p;
  float f[8];
  f[0] = bf2f(raw.x & 0xffffu); f[1] = bf2f(raw.x >> 16);
  f[2] = bf2f(raw.y & 0xffffu); f[3] = bf2f(raw.y >> 16);
  f[4] = bf2f(raw.z & 0xffffu); f[5] = bf2f(raw.z >> 16);
  f[6] = bf2f(raw.w & 0xffffu); f[7] = bf2f(raw.w >> 16);
  float ss = 0.f;
  #pragma unroll
  for (int j = 0; j < 8; ++j) ss += f[j] * f[j];
  ss += __shfl_xor(ss, 16);                 // reduce over the 4 k-groups (lanes ^16, ^32)
  ss += __shfl_xor(ss, 32);
  float inv = s / fmaxf(sqrtf(ss), 1e-12f);
  bf16x8 v;
  #pragma unroll
  for (int j = 0; j < 8; ++j) v[j] = (short)f2bf(f[j] * inv);
  return v;
}

__global__ __launch_bounds__(64, 2) void attn_win(const unsigned short* __restrict__ qkv,
    const float* __restrict__ bias16, const float* __restrict__ flex,
    unsigned short* __restrict__ aout) {
  __shared__ __align__(16) char smem[16640];     // one wave, one region
  float* S           = (float*)smem;             // [64][65] fp32 logits (stride 65: CF)
  unsigned short* P  = (unsigned short*)smem;    // [64][72] bf16, aliases S rows 0..35
  unsigned short* vT = (unsigned short*)(smem + 9216);  // [32][72] bf16, aliases S rows 35..54
  const int l = threadIdx.x;                     // 0..63
  const int lr = l & 15, lg = l >> 4;
  // XCD-bijective swizzle (grid 32768 % 8 == 0): 16 heads of a window -> same XCD
  const int g = (blockIdx.x & 7) * (gridDim.x >> 3) + (blockIdx.x >> 3);
  const int b = g >> 4;
  const int h = g & 15;
  const unsigned short* base = qkv + (size_t)b * NTOK * QKVN;
  const float scale = __expf(fminf(flex[h], 4.6051701860f));   // min(flex, ln 100)

  // early V load (T14): issue before QK^T so HBM latency hides under MFMA+softmax
  const uint4* vp = (const uint4*)(base + (size_t)l * QKVN + 2 * EMB + h * 32);
  uint4 v0 = vp[0], v1 = vp[1], v2 = vp[2], v3 = vp[3];

  // q (scale folded in) and k fragments, L2-normalized in-register
  bf16x8 aq[4], bk[4];
  #pragma unroll
  for (int i = 0; i < 4; ++i)
    aq[i] = load_norm_frag(base + (size_t)(i * 16 + lr) * QKVN + h * 32 + lg * 8, scale);
  #pragma unroll
  for (int i = 0; i < 4; ++i)
    bk[i] = load_norm_frag(base + (size_t)(i * 16 + lr) * QKVN + EMB + h * 32 + lg * 8, 1.f);

  // S = (scale * qn) @ kn^T
  const f32x4 z = (f32x4){0.f, 0.f, 0.f, 0.f};
  f32x4 sacc[4][4];
  #pragma unroll
  for (int i = 0; i < 4; ++i)
    #pragma unroll
    for (int j = 0; j < 4; ++j)
      sacc[i][j] = __builtin_amdgcn_mfma_f32_16x16x32_bf16(aq[i], bk[j], z, 0, 0, 0);

  // S + bias -> LDS (b32 scatter, stride 65: conflict-free)
  const float* bh = bias16 + (size_t)h * 4096;
  #pragma unroll
  for (int i = 0; i < 4; ++i)
    #pragma unroll
    for (int j = 0; j < 4; ++j)
      #pragma unroll
      for (int r = 0; r < 4; ++r) {
        int row = i * 16 + lg * 4 + r, col = j * 16 + lr;
        S[row * 65 + col] = sacc[i][j][r] + bh[row * 64 + col];
      }

  // per-lane row softmax (lane l owns row l). All S reads precede P/vT writes
  // in wave program order; asm fences stop compiler reordering across the alias.
  float rowv[64];
  float mx = -1e30f;
  #pragma unroll
  for (int j = 0; j < 64; ++j) { rowv[j] = S[l * 65 + j]; mx = fmaxf(mx, rowv[j]); }
  asm volatile("" ::: "memory");                 // S reads done; P/vT writes may begin
  float sum = 0.f;
  #pragma unroll
  for (int s = 0; s < 8; ++s) {                  // packed b128 P writes (bank-floor)
    bf16x8 pk;
    #pragma unroll
    for (int m = 0; m < 8; ++m) {
      float e = __expf(rowv[s * 8 + m] - mx);
      sum += e;
      pk[m] = (short)f2bf(e);
    }
    *(bf16x8*)(P + l * 72 + s * 8) = pk;
  }
  const float inv = 1.f / sum;

  // vT[d][tok] from preloaded regs (b16 scatter, stride 72: 2-way = free)
  {
    unsigned int wd[16] = {v0.x, v0.y, v0.z, v0.w, v1.x, v1.y, v1.z, v1.w,
                           v2.x, v2.y, v2.z, v2.w, v3.x, v3.y, v3.z, v3.w};
    #pragma unroll
    for (int d = 0; d < 32; ++d) {
      unsigned short val = (d & 1) ? (unsigned short)(wd[d >> 1] >> 16)
                                   : (unsigned short)(wd[d >> 1] & 0xffffu);
      vT[d * 72 + l] = val;
    }
  }
  asm volatile("" ::: "memory");                 // P/vT visible to the PV reads below

  // O = P @ V  (A = P rows, B = vT rows, both k-contiguous)
  f32x4 oacc[4][2];
  #pragma unroll
  for (int i = 0; i < 4; ++i) { oacc[i][0] = z; oacc[i][1] = z; }
  #pragma unroll
  for (int ks = 0; ks < 2; ++ks) {
    bf16x8 ap[4], bv[2];
    #pragma unroll
    for (int i = 0; i < 4; ++i)
      ap[i] = *(const bf16x8*)(P + (i * 16 + lr) * 72 + ks * 32 + lg * 8);
    #pragma unroll
    for (int jd = 0; jd < 2; ++jd)
      bv[jd] = *(const bf16x8*)(vT + (jd * 16 + lr) * 72 + ks * 32 + lg * 8);
    #pragma unroll
    for (int i = 0; i < 4; ++i)
      #pragma unroll
      for (int jd = 0; jd < 2; ++jd)
        oacc[i][jd] = __builtin_amdgcn_mfma_f32_16x16x32_bf16(ap[i], bv[jd], oacc[i][jd], 0, 0, 0);
  }
  // write attn-out (B,N,H*D) bf16, normalizing by rowsum (broadcast via shfl)
  #pragma unroll
  for (int i = 0; i < 4; ++i)
    #pragma unroll
    for (int jd = 0; jd < 2; ++jd)
      #pragma unroll
      for (int r = 0; r < 4; ++r) {
        int tok = i * 16 + lg * 4 + r, d = jd * 16 + lr;
        float val = oacc[i][jd][r] * __shfl(inv, tok);
        aout[(size_t)(b * NTOK + tok) * EMB + h * 32 + d] = f2bf(val);
      }
}

// ---------------- launch ----------------
extern "C" void kernel_launch(void* const* d_in, const int* in_sizes, int n_in,
                              void* d_out, int out_size, void* d_ws, size_t ws_size,
                              hipStream_t stream) {
  const float* x         = (const float*)d_in[0];
  const float* qkv_w     = (const float*)d_in[1];
  const float* q_bias    = (const float*)d_in[2];
  const float* v_bias    = (const float*)d_in[3];
  const float* flex      = (const float*)d_in[4];
  const float* cpb_w1    = (const float*)d_in[5];
  const float* cpb_b1    = (const float*)d_in[6];
  const float* cpb_w2    = (const float*)d_in[7];
  const float* proj_w    = (const float*)d_in[8];
  const float* proj_b    = (const float*)d_in[9];
  const float* rel_table = (const float*)d_in[10];
  const int*   rel_index = (const int*)d_in[11];

  char* ws = (char*)d_ws;
  unsigned short* qkv_bf = (unsigned short*)(ws + 0);                  // 402,653,184 B
  // xb (bf16 x) and ao_bf ALIAS: xb dies when the QKV GEMM finishes; ao_bf is
  // born at attn_win. Both are 134,217,728 B and fully rewritten every call.
  unsigned short* xb     = (unsigned short*)(ws + 402653184ull);
  unsigned short* ao_bf  = (unsigned short*)(ws + 402653184ull);
  unsigned short* wq_bf  = (unsigned short*)(ws + 536870912ull);       //   1,572,864 B
  unsigned short* wp_bf  = (unsigned short*)(ws + 538443776ull);       //     524,288 B
  float* qkv_bias        = (float*)(ws + 538968064ull);                //       6,144 B
  float* tab             = (float*)(ws + 538974208ull);                //      14,400 B
  float* bias16          = (float*)(ws + 538988608ull);                //     262,144 B

  xcast<<<32768, 256, 0, stream>>>(x, xb);
  prep_weights<<<3072, 256, 0, stream>>>(qkv_w, proj_w, q_bias, v_bias, wq_bf, wp_bf, qkv_bias);
  cpb_mlp<<<225, 64, 0, stream>>>(rel_table, cpb_w1, cpb_b1, cpb_w2, tab);
  cpb_expand<<<256, 256, 0, stream>>>(tab, rel_index, bias16);
  // QKV: M=131072, N=1536 -> grid 512*6 = 3072 (divisible by 8)
  gemm256<false, 6, EMB><<<3072, 512, 0, stream>>>(
      xb, wq_bf, qkv_bias, (void*)qkv_bf, MROWS, QKVN);
  attn_win<<<BWIN * HEADS, 64, 0, stream>>>(qkv_bf, bias16, flex, ao_bf);
  // proj: M=131072, N=512 -> grid 512*2 = 1024 (divisible by 8)
  gemm256<true, 2, EMB><<<1024, 512, 0, stream>>>(
      ao_bf, wp_bf, proj_b, d_out, MROWS, EMB);
}